// Round 5
// baseline (144.646 us; speedup 1.0000x reference)
//
#include <hip/hip_runtime.h>
#include <hip/hip_bf16.h>

// DirectEncodingModel via MFMA. Per group, (16 rows x 24) @ (24x16) is ONE
// v_mfma_f32_16x16x32_bf16 (K padded 24->32; bias rides in k=24 against a
// pad column fixed to 1.0 -- R12: pad column GONE, see below). Block =
// 1024 thr (16 waves) owns a 16-row acc tile in dynamic LDS; wave w does
// 4 groups/layer.
// R7: acc row stride 3588 u16 (7176 B, 1794 dw == 2 mod 32). Persistent
// blocks: grid=256 (1/CU), 4 tiles each; next x tile prefetched into
// VGPRs by waves 8-15 during the head, dumped to LDS at tile boundary.
// R11: two-kernel prepass (ws poison ~86us is unconditional -> d_ws free);
// operand swap mfma(W, af) -> lane holds 4 consecutive features of its own
// batch row nn (uint2 C-write, float4 head store); offsets packed u16.
// R12: (a) PAD-SKIP: quad3's gathers (k=24..31) are all constants -- k=24
// multiplies the bias against 1.0, k=25..31 multiply ZERO weight entries.
// Set af={1.0,0..} in regs under `if (quad<3)` exec-mask: -25% gather
// bank-work, -25% offset b128 traffic; ONE/ZERO pad columns + init
// removed. Head s=1: quads 0-1 real, quad2 af[0]=1.0 (k=48), quad3 zero.
// (b) SOFTWARE PIPELINE: layer l+1's ofs (LDS) + bfr (global L2) loads
// issue right after layer l's MFMAs (af/bfr dead -> live ~70 VGPR), hiding
// their ~120/200cy latency under tanh/pack/write + barrier. L0's loads
// hide under the x dump; head's loads hide under L2's write phase.
// Numerics bit-identical to R11 (absmax 0.015625).
// Layouts (HW-verified): A[m=lane&15][k=(lane>>4)*8+j];
//   B[k=(lane>>4)*8+j][n=lane&15]; C/D col=lane&15, row=(lane>>4)*4+reg.

typedef unsigned short ushort_t;
typedef unsigned int uint_t;
typedef __attribute__((ext_vector_type(8))) short short8;   // 8 bf16 frag
typedef __attribute__((ext_vector_type(4))) float f32x4;    // MFMA acc

#define ACC_STRIDE 3588                   // u16 per row; 7176 B = 1794 dw == 2 mod 32
#define ROW_BYTES (ACC_STRIDE * 2)
#define PAD_ONE 3584                      // (legacy) pad col; only convert refs it
#define ONE_BYTE (PAD_ONE * 2)            // 7168
#define ZERO_BYTE (3586 * 2)              // 7172
#define ACC_U16 (16 * ACC_STRIDE)         // 57408 u16 = 114816 B
#define OFFS_U16 6400                     // hidden 6144 + head 256 (u16 each)
#define LDS_BYTES (ACC_U16 * 2 + OFFS_U16 * 2)   // 127616 B

// d_ws layout (bytes)
#define OFF_HIDO_B 204800                 // after 12800 frags * 16 B
#define OFF_HEADO_B (204800 + 12288)      // hidden offs 6144 * 2 B

#define BF16_ONE ((short)0x3f80)          // bf16 1.0

__device__ __forceinline__ ushort_t f2bf(float f) {
    __hip_bfloat16 h = __float2bfloat16(f);
    union { __hip_bfloat16 h; ushort_t u; } v;
    v.h = h;
    return v.u;
}

__device__ __forceinline__ uint_t pack2bf(float lo, float hi) {
    return (uint_t)f2bf(lo) | ((uint_t)f2bf(hi) << 16);
}

// tanh(x) = 1 - 2/(e^2x + 1); exp saturation gives exact +-1 tails, no clamp.
__device__ __forceinline__ float fast_tanh(float x) {
    float e = __expf(2.0f * x);
    return fmaf(-2.0f, __builtin_amdgcn_rcpf(e + 1.0f), 1.0f);
}

// 8 LDS gathers from one uint4 of packed u16 byte-offsets
__device__ __forceinline__ void gather8(const char* accb, uint4 o, short8& af) {
    af[0] = *(const short*)(accb + (o.x & 0xffffu));
    af[1] = *(const short*)(accb + (o.x >> 16));
    af[2] = *(const short*)(accb + (o.y & 0xffffu));
    af[3] = *(const short*)(accb + (o.y >> 16));
    af[4] = *(const short*)(accb + (o.z & 0xffffu));
    af[5] = *(const short*)(accb + (o.z >> 16));
    af[6] = *(const short*)(accb + (o.w & 0xffffu));
    af[7] = *(const short*)(accb + (o.w >> 16));
}

// ---- Pre-pack weights (B-frag order, bias in k=24/k=48 slot) + offsets ----
__global__ __launch_bounds__(256)
void convert_weights(const float* __restrict__ W1, const float* __restrict__ b1,
                     const float* __restrict__ W2, const float* __restrict__ b2,
                     const float* __restrict__ W3, const float* __restrict__ b3,
                     const float* __restrict__ Wo, const float* __restrict__ bo,
                     const int* __restrict__ idx1, const int* __restrict__ idx2,
                     const int* __restrict__ idx3, const int* __restrict__ idxo,
                     ushort_t* __restrict__ ws)
{
    const int tid = blockIdx.x * 256 + threadIdx.x;
    const int lane = tid & 63;
    const int nn = lane & 15;
    const int quad = lane >> 4;
    if (tid < 12288) {
        const int g = (tid >> 6) & 63;
        const int l = tid >> 12;   // 0..2
        const float* W = (l == 0) ? W1 : (l == 1) ? W2 : W3;
        const float* bb = (l == 0) ? b1 : (l == 1) ? b2 : b3;
        const float* Wg = W + g * 384;
        ushort_t v[8];
        #pragma unroll
        for (int j = 0; j < 8; ++j) {
            const int k = quad * 8 + j;
            v[j] = (k < 24) ? f2bf(Wg[k * 16 + nn])
                 : (k == 24) ? f2bf(bb[g * 16 + nn]) : (ushort_t)0;
        }
        ushort4* dst = reinterpret_cast<ushort4*>(ws + (size_t)tid * 8);
        dst[0] = make_ushort4(v[0], v[1], v[2], v[3]);
        dst[1] = make_ushort4(v[4], v[5], v[6], v[7]);
    } else if (tid < 12800) {
        const int h = tid - 12288;
        const int gs = h >> 6;          // 0..7: go*2+step
        const int go = gs >> 1;
        const int step = gs & 1;
        const float* Wg = Wo + go * 768;
        ushort_t v[8];
        #pragma unroll
        for (int j = 0; j < 8; ++j) {
            const int k = step * 32 + quad * 8 + j;
            v[j] = (k < 48) ? f2bf(Wg[k * 16 + nn])
                 : (k == 48) ? f2bf(bo[go * 16 + nn]) : (ushort_t)0;
        }
        ushort4* dst = reinterpret_cast<ushort4*>(ws + (size_t)tid * 8);
        dst[0] = make_ushort4(v[0], v[1], v[2], v[3]);
        dst[1] = make_ushort4(v[4], v[5], v[6], v[7]);
    } else if (tid < 18944) {
        // hidden gather byte-offsets (u16), frag order: e = l*2048 + g*32 + k
        const int e = tid - 12800;
        const int l = e >> 11;
        const int rem = e & 2047;
        const int g = rem >> 5;
        const int k = rem & 31;
        const int* idx = (l == 0) ? idx1 : (l == 1) ? idx2 : idx3;
        const int v = (k < 24) ? idx[g * 24 + k] * 2
                    : (k == 24) ? ONE_BYTE : ZERO_BYTE;   // k>=24 unread (R12)
        reinterpret_cast<ushort_t*>((char*)ws + OFF_HIDO_B)[e] = (ushort_t)v;
    } else if (tid < 19200) {
        // head gather byte-offsets (u16): e = go*64 + k
        const int e = tid - 18944;
        const int go = e >> 6;
        const int k = e & 63;
        const int v = (k < 48) ? idxo[go * 48 + k] * 2
                    : (k == 48) ? ONE_BYTE : ZERO_BYTE;   // k>=48 unread (R12)
        reinterpret_cast<ushort_t*>((char*)ws + OFF_HEADO_B)[e] = (ushort_t)v;
    }
}

#define NTILES 4   // 16384 rows / 16 per tile / 256 blocks

__global__ __launch_bounds__(1024)
void demodel_mfma(const float* __restrict__ x,
                  const ushort_t* __restrict__ ws,
                  float* __restrict__ out)
{
    extern __shared__ __align__(16) ushort_t smem[];
    const int t = threadIdx.x;
    const int lane = t & 63;
    const int wv = t >> 6;               // wave 0..15
    const int nn = lane & 15;
    const int quad = lane >> 4;

    // ---- stage packed u16 offset tables: 12800 B global -> LDS ----
    {
        const uint4* src = reinterpret_cast<const uint4*>((const char*)ws + OFF_HIDO_B);
        uint4* dst = reinterpret_cast<uint4*>(smem + ACC_U16);
        for (int i = t; i < (OFFS_U16 * 2) / 16; i += 1024)   // 800 uint4
            dst[i] = src[i];
    }

    const ushort_t* offsu = smem + ACC_U16;                  // u16 table
    const char* accb = (const char*)smem + nn * ROW_BYTES;   // lane's row nn
    char* accw = (char*)smem;
    const int g0 = wv << 2;

    // prefetch regs for the x tile (waves 8..15: 512 thr x 16 floats)
    const int pr = (t - 512) >> 5;        // row 0..15 (valid for wv>=8)
    const int pc = (t & 31) << 4;         // float col 0..496
    uint_t px[8];

    // ---- prefetch tile 0 ----
    if (wv >= 8) {
        const float4* src = reinterpret_cast<const float4*>(
            x + ((size_t)blockIdx.x * 16 + pr) * 512 + pc);
        float4 a0 = src[0], a1 = src[1], a2 = src[2], a3 = src[3];
        px[0] = pack2bf(a0.x, a0.y); px[1] = pack2bf(a0.z, a0.w);
        px[2] = pack2bf(a1.x, a1.y); px[3] = pack2bf(a1.z, a1.w);
        px[4] = pack2bf(a2.x, a2.y); px[5] = pack2bf(a2.z, a2.w);
        px[6] = pack2bf(a3.x, a3.y); px[7] = pack2bf(a3.z, a3.w);
    }

// load layer L's weights (all lanes) + offsets (quads 0..2 only)
#define LOAD_HIDDEN(L, OFS, BFR)                                            \
    {                                                                       \
        _Pragma("unroll")                                                   \
        for (int gi = 0; gi < 4; ++gi)                                      \
            BFR[gi] = *reinterpret_cast<const short8*>(                     \
                ws + (((size_t)(L) * 64 + g0 + gi) * 64 + lane) * 8);       \
        if (quad < 3) {                                                     \
            _Pragma("unroll")                                               \
            for (int gi = 0; gi < 4; ++gi)                                  \
                OFS[gi] = *reinterpret_cast<const uint4*>(                  \
                    offsu + (L) * 2048 + (g0 + gi) * 32 + quad * 8);        \
        }                                                                   \
    }

// gather af for 4 groups; quad3 = constants (k=24 -> 1.0, k=25..31 x W=0)
#define GATHER_PRED(OFS, AF)                                                \
    {                                                                       \
        if (quad < 3) {                                                     \
            _Pragma("unroll")                                               \
            for (int gi = 0; gi < 4; ++gi) gather8(accb, OFS[gi], AF[gi]);  \
        } else {                                                            \
            _Pragma("unroll")                                               \
            for (int gi = 0; gi < 4; ++gi) {                                \
                short8 c = {};                                              \
                c[0] = BF16_ONE;                                            \
                AF[gi] = c;                                                 \
            }                                                               \
        }                                                                   \
    }

#define MFMA4(BFR, AF, ACC)                                                 \
    {                                                                       \
        _Pragma("unroll")                                                   \
        for (int gi = 0; gi < 4; ++gi) {                                    \
            f32x4 z = { 0.f, 0.f, 0.f, 0.f };                               \
            ACC[gi] = __builtin_amdgcn_mfma_f32_16x16x32_bf16(              \
                BFR[gi], AF[gi], z, 0, 0, 0);                               \
        }                                                                   \
    }

#define WRITE_TANH(L, ACC)                                                  \
    {                                                                       \
        _Pragma("unroll")                                                   \
        for (int gi = 0; gi < 4; ++gi) {                                    \
            const int colo = 512 + (L) * 1024 + (g0 + gi) * 16 + quad * 4;  \
            uint2 w = make_uint2(                                           \
                pack2bf(fast_tanh(ACC[gi][0]), fast_tanh(ACC[gi][1])),      \
                pack2bf(fast_tanh(ACC[gi][2]), fast_tanh(ACC[gi][3])));     \
            *reinterpret_cast<uint2*>(accw + nn * ROW_BYTES + colo * 2) = w;\
        }                                                                   \
    }

    #pragma unroll 1
    for (int it = 0; it < NTILES; ++it) {
        const int row0 = (it * 256 + blockIdx.x) * 16;

        __syncthreads();   // prev tile's head gathers done -> x region free
        if (wv >= 8) {     // dump prefetched x: 16 u16 = 32 B as 4x b64
            uint2* d = reinterpret_cast<uint2*>(accw + pr * ROW_BYTES + pc * 2);
            d[0] = make_uint2(px[0], px[1]);
            d[1] = make_uint2(px[2], px[3]);
            d[2] = make_uint2(px[4], px[5]);
            d[3] = make_uint2(px[6], px[7]);
        }
        // L0 prefetch overlaps the dump + barrier drain
        uint4 ofsA[4]; short8 bfrA[4];
        LOAD_HIDDEN(0, ofsA, bfrA)
        __syncthreads();

        // ---- layer 0 ----
        short8 af[4];
        f32x4 acc[4];
        GATHER_PRED(ofsA, af)
        MFMA4(bfrA, af, acc)
        uint4 ofsB[4]; short8 bfrB[4];
        LOAD_HIDDEN(1, ofsB, bfrB)          // hides under tanh/write+barrier
        WRITE_TANH(0, acc)
        __syncthreads();

        // ---- layer 1 ----
        GATHER_PRED(ofsB, af)
        MFMA4(bfrB, af, acc)
        LOAD_HIDDEN(2, ofsA, bfrA)
        WRITE_TANH(1, acc)
        __syncthreads();

        // ---- layer 2 ----
        GATHER_PRED(ofsA, af)
        MFMA4(bfrA, af, acc)
        // head prefetch (waves 0..3) hides under L2's write phase
        uint4 hof0, hof1;
        short8 hbf0, hbf1;
        if (wv < 4) {
            hof0 = *reinterpret_cast<const uint4*>(
                offsu + 6144 + wv * 64 + quad * 8);
            if (quad < 2)
                hof1 = *reinterpret_cast<const uint4*>(
                    offsu + 6144 + wv * 64 + 32 + quad * 8);
            hbf0 = *reinterpret_cast<const short8*>(
                ws + (12288 + ((size_t)wv * 2 + 0) * 64 + lane) * 8);
            hbf1 = *reinterpret_cast<const short8*>(
                ws + (12288 + ((size_t)wv * 2 + 1) * 64 + lane) * 8);
        }
        WRITE_TANH(2, acc)
        __syncthreads();

        // ---- head (waves 0..3) and next-x prefetch (waves 8..15) ----
        if (wv < 4) {
            short8 af0, af1;
            gather8(accb, hof0, af0);               // k=0..31 all real
            if (quad < 2) {
                gather8(accb, hof1, af1);           // k=32..47 real
            } else {
                short8 c = {};
                if (quad == 2) c[0] = BF16_ONE;     // k=48 bias slot
                af1 = c;                            // k>48: Wo zeros
            }
            f32x4 z = { 0.f, 0.f, 0.f, 0.f };
            f32x4 a0 = __builtin_amdgcn_mfma_f32_16x16x32_bf16(hbf0, af0, z, 0, 0, 0);
            f32x4 a1 = __builtin_amdgcn_mfma_f32_16x16x32_bf16(hbf1, af1, z, 0, 0, 0);
            // lane holds out[row0+nn][wv*16 + quad*4 .. +3] -> one dwordx4
            float4 o;
            o.x = a0[0] + a1[0];
            o.y = a0[1] + a1[1];
            o.z = a0[2] + a1[2];
            o.w = a0[3] + a1[3];
            *reinterpret_cast<float4*>(
                out + (size_t)(row0 + nn) * 64 + wv * 16 + quad * 4) = o;
        }
        if (wv >= 8 && it + 1 < NTILES) {
            const float4* src = reinterpret_cast<const float4*>(
                x + (((size_t)(it + 1) * 256 + blockIdx.x) * 16 + pr) * 512 + pc);
            float4 a0 = src[0], a1 = src[1], a2 = src[2], a3 = src[3];
            px[0] = pack2bf(a0.x, a0.y); px[1] = pack2bf(a0.z, a0.w);
            px[2] = pack2bf(a1.x, a1.y); px[3] = pack2bf(a1.z, a1.w);
            px[4] = pack2bf(a2.x, a2.y); px[5] = pack2bf(a2.z, a2.w);
            px[6] = pack2bf(a3.x, a3.y); px[7] = pack2bf(a3.z, a3.w);
        }
    }
#undef LOAD_HIDDEN
#undef GATHER_PRED
#undef MFMA4
#undef WRITE_TANH
}

extern "C" void kernel_launch(void* const* d_in, const int* in_sizes, int n_in,
                              void* d_out, int out_size, void* d_ws, size_t ws_size,
                              hipStream_t stream) {
    const float* x  = (const float*)d_in[0];
    const float* W1 = (const float*)d_in[1];
    const float* b1 = (const float*)d_in[2];
    const float* W2 = (const float*)d_in[3];
    const float* b2 = (const float*)d_in[4];
    const float* W3 = (const float*)d_in[5];
    const float* b3 = (const float*)d_in[6];
    const float* Wo = (const float*)d_in[7];
    const float* bo = (const float*)d_in[8];
    const int* idx1 = (const int*)d_in[9];
    const int* idx2 = (const int*)d_in[10];
    const int* idx3 = (const int*)d_in[11];
    const int* idxo = (const int*)d_in[12];
    float* out = (float*)d_out;

    (void)hipFuncSetAttribute((const void*)demodel_mfma,
                              hipFuncAttributeMaxDynamicSharedMemorySize,
                              LDS_BYTES);

    convert_weights<<<75, 256, 0, stream>>>(W1, b1, W2, b2, W3, b3, Wo, bo,
                                            idx1, idx2, idx3, idxo,
                                            (ushort_t*)d_ws);

    demodel_mfma<<<256, 1024, LDS_BYTES, stream>>>(
        x, (const ushort_t*)d_ws, out);
}

// Round 6
// 121.277 us; speedup vs baseline: 1.1927x; 1.1927x over previous
//
#include <hip/hip_runtime.h>
#include <hip/hip_bf16.h>

// DirectEncodingModel via MFMA. Per group, (16 rows x 24) @ (24x16) is ONE
// v_mfma_f32_16x16x32_bf16 (K padded 24->32; bias rides in k=24 against an
// af slot fixed to 1.0 in registers). Block = 1024 thr (16 waves) owns a
// 16-row acc tile in dynamic LDS; wave w does 4 groups/layer.
// R7: acc row stride 3588 u16 (7176 B, 1794 dw == 2 mod 32). Persistent
// blocks: grid=256 (1/CU), 4 tiles each; next x tile prefetched into
// VGPRs by waves 8-15 during the head, dumped to LDS at tile boundary.
// R11 (kept): two-kernel prepass (ws poison ~86us unconditional -> d_ws
// free); operand swap mfma(W, af) -> lane holds 4 consecutive features of
// its own batch row nn (uint2 C-write, float4 head store); offsets u16.
// R13 = R11 + pad-skip ONLY. R12's cross-barrier software pipeline caused
// massive scratch spills (FETCH 88MB / WRITE 50MB, VGPR_Count=64 -> the
// held ofs/bfr sets spilled; demodel 31->58us). Lesson: NOTHING lives
// across a barrier except px. Pad-skip: quad3's gathers (k=24..31) are
// constants -- k=24 multiplies bias vs 1.0, k=25..31 multiply ZERO weight
// entries -> af={1.0,0..} in regs under exec-mask; -25% gather issue,
// -25% offset b128 traffic. Head s=1: quads 0-1 real, quad2 af[0]=1.0
// (k=48 bias), quad3 zeros. Numerics bit-identical (absmax 0.015625).
// Layouts (HW-verified): A[m=lane&15][k=(lane>>4)*8+j];
//   B[k=(lane>>4)*8+j][n=lane&15]; C/D col=lane&15, row=(lane>>4)*4+reg.

typedef unsigned short ushort_t;
typedef unsigned int uint_t;
typedef __attribute__((ext_vector_type(8))) short short8;   // 8 bf16 frag
typedef __attribute__((ext_vector_type(4))) float f32x4;    // MFMA acc

#define ACC_STRIDE 3588                   // u16 per row; 7176 B = 1794 dw == 2 mod 32
#define ROW_BYTES (ACC_STRIDE * 2)
#define PAD_ONE 3584                      // (legacy) pad col; only convert refs it
#define ONE_BYTE (PAD_ONE * 2)            // 7168
#define ZERO_BYTE (3586 * 2)              // 7172
#define ACC_U16 (16 * ACC_STRIDE)         // 57408 u16 = 114816 B
#define OFFS_U16 6400                     // hidden 6144 + head 256 (u16 each)
#define LDS_BYTES (ACC_U16 * 2 + OFFS_U16 * 2)   // 127616 B

// d_ws layout (bytes)
#define OFF_HIDO_B 204800                 // after 12800 frags * 16 B
#define OFF_HEADO_B (204800 + 12288)      // hidden offs 6144 * 2 B

#define BF16_ONE ((short)0x3f80)          // bf16 1.0

__device__ __forceinline__ ushort_t f2bf(float f) {
    __hip_bfloat16 h = __float2bfloat16(f);
    union { __hip_bfloat16 h; ushort_t u; } v;
    v.h = h;
    return v.u;
}

__device__ __forceinline__ uint_t pack2bf(float lo, float hi) {
    return (uint_t)f2bf(lo) | ((uint_t)f2bf(hi) << 16);
}

// tanh(x) = 1 - 2/(e^2x + 1); exp saturation gives exact +-1 tails, no clamp.
__device__ __forceinline__ float fast_tanh(float x) {
    float e = __expf(2.0f * x);
    return fmaf(-2.0f, __builtin_amdgcn_rcpf(e + 1.0f), 1.0f);
}

// 8 LDS gathers from one uint4 of packed u16 byte-offsets
__device__ __forceinline__ void gather8(const char* accb, uint4 o, short8& af) {
    af[0] = *(const short*)(accb + (o.x & 0xffffu));
    af[1] = *(const short*)(accb + (o.x >> 16));
    af[2] = *(const short*)(accb + (o.y & 0xffffu));
    af[3] = *(const short*)(accb + (o.y >> 16));
    af[4] = *(const short*)(accb + (o.z & 0xffffu));
    af[5] = *(const short*)(accb + (o.z >> 16));
    af[6] = *(const short*)(accb + (o.w & 0xffffu));
    af[7] = *(const short*)(accb + (o.w >> 16));
}

// ---- Pre-pack weights (B-frag order, bias in k=24/k=48 slot) + offsets ----
__global__ __launch_bounds__(256)
void convert_weights(const float* __restrict__ W1, const float* __restrict__ b1,
                     const float* __restrict__ W2, const float* __restrict__ b2,
                     const float* __restrict__ W3, const float* __restrict__ b3,
                     const float* __restrict__ Wo, const float* __restrict__ bo,
                     const int* __restrict__ idx1, const int* __restrict__ idx2,
                     const int* __restrict__ idx3, const int* __restrict__ idxo,
                     ushort_t* __restrict__ ws)
{
    const int tid = blockIdx.x * 256 + threadIdx.x;
    const int lane = tid & 63;
    const int nn = lane & 15;
    const int quad = lane >> 4;
    if (tid < 12288) {
        const int g = (tid >> 6) & 63;
        const int l = tid >> 12;   // 0..2
        const float* W = (l == 0) ? W1 : (l == 1) ? W2 : W3;
        const float* bb = (l == 0) ? b1 : (l == 1) ? b2 : b3;
        const float* Wg = W + g * 384;
        ushort_t v[8];
        #pragma unroll
        for (int j = 0; j < 8; ++j) {
            const int k = quad * 8 + j;
            v[j] = (k < 24) ? f2bf(Wg[k * 16 + nn])
                 : (k == 24) ? f2bf(bb[g * 16 + nn]) : (ushort_t)0;
        }
        ushort4* dst = reinterpret_cast<ushort4*>(ws + (size_t)tid * 8);
        dst[0] = make_ushort4(v[0], v[1], v[2], v[3]);
        dst[1] = make_ushort4(v[4], v[5], v[6], v[7]);
    } else if (tid < 12800) {
        const int h = tid - 12288;
        const int gs = h >> 6;          // 0..7: go*2+step
        const int go = gs >> 1;
        const int step = gs & 1;
        const float* Wg = Wo + go * 768;
        ushort_t v[8];
        #pragma unroll
        for (int j = 0; j < 8; ++j) {
            const int k = step * 32 + quad * 8 + j;
            v[j] = (k < 48) ? f2bf(Wg[k * 16 + nn])
                 : (k == 48) ? f2bf(bo[go * 16 + nn]) : (ushort_t)0;
        }
        ushort4* dst = reinterpret_cast<ushort4*>(ws + (size_t)tid * 8);
        dst[0] = make_ushort4(v[0], v[1], v[2], v[3]);
        dst[1] = make_ushort4(v[4], v[5], v[6], v[7]);
    } else if (tid < 18944) {
        // hidden gather byte-offsets (u16), frag order: e = l*2048 + g*32 + k
        const int e = tid - 12800;
        const int l = e >> 11;
        const int rem = e & 2047;
        const int g = rem >> 5;
        const int k = rem & 31;
        const int* idx = (l == 0) ? idx1 : (l == 1) ? idx2 : idx3;
        const int v = (k < 24) ? idx[g * 24 + k] * 2
                    : (k == 24) ? ONE_BYTE : ZERO_BYTE;   // k>=24 unread (R13)
        reinterpret_cast<ushort_t*>((char*)ws + OFF_HIDO_B)[e] = (ushort_t)v;
    } else if (tid < 19200) {
        // head gather byte-offsets (u16): e = go*64 + k
        const int e = tid - 18944;
        const int go = e >> 6;
        const int k = e & 63;
        const int v = (k < 48) ? idxo[go * 48 + k] * 2
                    : (k == 48) ? ONE_BYTE : ZERO_BYTE;   // k>=48 unread (R13)
        reinterpret_cast<ushort_t*>((char*)ws + OFF_HEADO_B)[e] = (ushort_t)v;
    }
}

#define NTILES 4   // 16384 rows / 16 per tile / 256 blocks

__global__ __launch_bounds__(1024)
void demodel_mfma(const float* __restrict__ x,
                  const ushort_t* __restrict__ ws,
                  float* __restrict__ out)
{
    extern __shared__ __align__(16) ushort_t smem[];
    const int t = threadIdx.x;
    const int lane = t & 63;
    const int wv = t >> 6;               // wave 0..15
    const int nn = lane & 15;
    const int quad = lane >> 4;

    // ---- stage packed u16 offset tables: 12800 B global -> LDS ----
    {
        const uint4* src = reinterpret_cast<const uint4*>((const char*)ws + OFF_HIDO_B);
        uint4* dst = reinterpret_cast<uint4*>(smem + ACC_U16);
        for (int i = t; i < (OFFS_U16 * 2) / 16; i += 1024)   // 800 uint4
            dst[i] = src[i];
    }

    const ushort_t* offsu = smem + ACC_U16;                  // u16 table
    const char* accb = (const char*)smem + nn * ROW_BYTES;   // lane's row nn
    char* accw = (char*)smem;

    // prefetch regs for the x tile (waves 8..15: 512 thr x 16 floats)
    const int pr = (t - 512) >> 5;        // row 0..15 (valid for wv>=8)
    const int pc = (t & 31) << 4;         // float col 0..496
    uint_t px[8];

    // ---- prefetch tile 0 ----
    if (wv >= 8) {
        const float4* src = reinterpret_cast<const float4*>(
            x + ((size_t)blockIdx.x * 16 + pr) * 512 + pc);
        float4 a0 = src[0], a1 = src[1], a2 = src[2], a3 = src[3];
        px[0] = pack2bf(a0.x, a0.y); px[1] = pack2bf(a0.z, a0.w);
        px[2] = pack2bf(a1.x, a1.y); px[3] = pack2bf(a1.z, a1.w);
        px[4] = pack2bf(a2.x, a2.y); px[5] = pack2bf(a2.z, a2.w);
        px[6] = pack2bf(a3.x, a3.y); px[7] = pack2bf(a3.z, a3.w);
    }

    #pragma unroll 1
    for (int it = 0; it < NTILES; ++it) {
        const int row0 = (it * 256 + blockIdx.x) * 16;

        __syncthreads();   // prev tile's head gathers done -> x region free
        if (wv >= 8) {     // dump prefetched x: 16 u16 = 32 B as 4x b64
            uint2* d = reinterpret_cast<uint2*>(accw + pr * ROW_BYTES + pc * 2);
            d[0] = make_uint2(px[0], px[1]);
            d[1] = make_uint2(px[2], px[3]);
            d[2] = make_uint2(px[4], px[5]);
            d[3] = make_uint2(px[6], px[7]);
        }
        __syncthreads();

        // ---- 3 hidden layers (R11 structure: all loads adjacent to use) --
        #pragma unroll 1
        for (int l = 0; l < 3; ++l) {
            const int out_base = 512 + l * 1024;
            const int g0 = wv << 2;

            short8 bfr[4];
            #pragma unroll
            for (int gi = 0; gi < 4; ++gi)
                bfr[gi] = *reinterpret_cast<const short8*>(
                    ws + (((size_t)l * 64 + g0 + gi) * 64 + lane) * 8);

            // pad-skip: quad3 gathers nothing (k=24 -> bias x 1.0 in regs,
            // k=25..31 multiply zero weight entries)
            short8 af[4];
            if (quad < 3) {
                uint4 ofs[4];
                #pragma unroll
                for (int gi = 0; gi < 4; ++gi)
                    ofs[gi] = *reinterpret_cast<const uint4*>(
                        offsu + l * 2048 + (g0 + gi) * 32 + quad * 8);
                #pragma unroll
                for (int gi = 0; gi < 4; ++gi)
                    gather8(accb, ofs[gi], af[gi]);
            } else {
                #pragma unroll
                for (int gi = 0; gi < 4; ++gi) {
                    short8 c = {};
                    c[0] = BF16_ONE;
                    af[gi] = c;
                }
            }

            f32x4 acc[4];
            #pragma unroll
            for (int gi = 0; gi < 4; ++gi) {
                f32x4 z = { 0.f, 0.f, 0.f, 0.f };
                // swapped: D = W^T * acc^T; lane holds 4 consecutive
                // features (quad*4+i) of its own batch row nn
                acc[gi] = __builtin_amdgcn_mfma_f32_16x16x32_bf16(bfr[gi], af[gi], z, 0, 0, 0);
            }

            #pragma unroll
            for (int gi = 0; gi < 4; ++gi) {
                const int colo = out_base + (g0 + gi) * 16 + quad * 4;
                uint2 w = make_uint2(
                    pack2bf(fast_tanh(acc[gi][0]), fast_tanh(acc[gi][1])),
                    pack2bf(fast_tanh(acc[gi][2]), fast_tanh(acc[gi][3])));
                *reinterpret_cast<uint2*>(accw + nn * ROW_BYTES + colo * 2) = w;
            }
            __syncthreads();
        }

        // ---- head (waves 0..3) and next-x prefetch (waves 8..15) ----
        if (wv < 4) {
            const int go = wv;
            short8 bfr0 = *reinterpret_cast<const short8*>(
                ws + (12288 + ((size_t)go * 2 + 0) * 64 + lane) * 8);
            short8 bfr1 = *reinterpret_cast<const short8*>(
                ws + (12288 + ((size_t)go * 2 + 1) * 64 + lane) * 8);

            // s=0: k=0..31 all real
            short8 af0;
            {
                uint4 o = *reinterpret_cast<const uint4*>(
                    offsu + 6144 + go * 64 + quad * 8);
                gather8(accb, o, af0);
            }
            // s=1: k=32..47 real (quads 0-1); quad2 k=48 bias slot; quad3 zero
            short8 af1;
            if (quad < 2) {
                uint4 o = *reinterpret_cast<const uint4*>(
                    offsu + 6144 + go * 64 + 32 + quad * 8);
                gather8(accb, o, af1);
            } else {
                short8 c = {};
                if (quad == 2) c[0] = BF16_ONE;
                af1 = c;
            }

            f32x4 z = { 0.f, 0.f, 0.f, 0.f };
            f32x4 a0 = __builtin_amdgcn_mfma_f32_16x16x32_bf16(bfr0, af0, z, 0, 0, 0);
            f32x4 a1 = __builtin_amdgcn_mfma_f32_16x16x32_bf16(bfr1, af1, z, 0, 0, 0);
            // lane holds out[row0+nn][go*16 + quad*4 .. +3] -> one dwordx4
            float4 o;
            o.x = a0[0] + a1[0];
            o.y = a0[1] + a1[1];
            o.z = a0[2] + a1[2];
            o.w = a0[3] + a1[3];
            *reinterpret_cast<float4*>(
                out + (size_t)(row0 + nn) * 64 + go * 16 + quad * 4) = o;
        }
        if (wv >= 8 && it + 1 < NTILES) {
            const float4* src = reinterpret_cast<const float4*>(
                x + (((size_t)(it + 1) * 256 + blockIdx.x) * 16 + pr) * 512 + pc);
            float4 a0 = src[0], a1 = src[1], a2 = src[2], a3 = src[3];
            px[0] = pack2bf(a0.x, a0.y); px[1] = pack2bf(a0.z, a0.w);
            px[2] = pack2bf(a1.x, a1.y); px[3] = pack2bf(a1.z, a1.w);
            px[4] = pack2bf(a2.x, a2.y); px[5] = pack2bf(a2.z, a2.w);
            px[6] = pack2bf(a3.x, a3.y); px[7] = pack2bf(a3.z, a3.w);
        }
    }
}

extern "C" void kernel_launch(void* const* d_in, const int* in_sizes, int n_in,
                              void* d_out, int out_size, void* d_ws, size_t ws_size,
                              hipStream_t stream) {
    const float* x  = (const float*)d_in[0];
    const float* W1 = (const float*)d_in[1];
    const float* b1 = (const float*)d_in[2];
    const float* W2 = (const float*)d_in[3];
    const float* b2 = (const float*)d_in[4];
    const float* W3 = (const float*)d_in[5];
    const float* b3 = (const float*)d_in[6];
    const float* Wo = (const float*)d_in[7];
    const float* bo = (const float*)d_in[8];
    const int* idx1 = (const int*)d_in[9];
    const int* idx2 = (const int*)d_in[10];
    const int* idx3 = (const int*)d_in[11];
    const int* idxo = (const int*)d_in[12];
    float* out = (float*)d_out;

    (void)hipFuncSetAttribute((const void*)demodel_mfma,
                              hipFuncAttributeMaxDynamicSharedMemorySize,
                              LDS_BYTES);

    convert_weights<<<75, 256, 0, stream>>>(W1, b1, W2, b2, W3, b3, Wo, bo,
                                            idx1, idx2, idx3, idxo,
                                            (ushort_t*)d_ws);

    demodel_mfma<<<256, 1024, LDS_BYTES, stream>>>(
        x, (const ushort_t*)d_ws, out);
}